// Round 8
// baseline (947.375 us; speedup 1.0000x reference)
//
#include <hip/hip_runtime.h>

#define S 4096
#define D 64
#define NB 16

typedef _Float16 half8 __attribute__((ext_vector_type(8)));
typedef _Float16 half2v __attribute__((ext_vector_type(2)));
typedef float f32x4 __attribute__((ext_vector_type(4)));
typedef int int4v __attribute__((ext_vector_type(4)));

// ---- Prepass A: Q (scaled by 1/8) and K -> fp16 ----
__global__ void cvt_qk(const float* __restrict__ Q, const float* __restrict__ K,
                       _Float16* __restrict__ Qh, _Float16* __restrict__ Kh, int n) {
  int i = blockIdx.x * blockDim.x + threadIdx.x;
  int stride = gridDim.x * blockDim.x;
  for (; i < n; i += stride) {
    Qh[i] = (_Float16)(Q[i] * 0.125f);   // fold 1/TEMPERATURE into Q
    Kh[i] = (_Float16)(K[i]);
  }
}

// ---- Prepass B: V -> fp16 transposed Vt[b][d][s] ----
__global__ void cvt_vt(const float* __restrict__ V, _Float16* __restrict__ Vt) {
  __shared__ float tile[64][65];
  int b = blockIdx.x >> 6;
  int s0 = (blockIdx.x & 63) * 64;
  const float* vb = V + ((size_t)b * S) * D;
  for (int i = threadIdx.x; i < 64 * 64; i += 256) {
    int sl = i >> 6, d = i & 63;
    tile[sl][d] = vb[(size_t)(s0 + sl) * D + d];
  }
  __syncthreads();
  _Float16* vtb = Vt + ((size_t)b * D) * S;
  for (int i = threadIdx.x; i < 64 * 64; i += 256) {
    int dl = i >> 6, sl = i & 63;
    vtb[(size_t)dl * S + s0 + sl] = (_Float16)tile[sl][dl];
  }
}

// ---- Pass 1: X = softmax(QK^T)V and Lsum = log(rowsum(exp)) ----
// Swapped QK^T (mfma(K,Q)): lane holds score[key=4lq+j][query=l15] -> PV
// A-frags rebuilt via in-register shfl transpose. NO LDS / NO fences in the
// chunk loop: R2-R7 were latency-serialized (~1700cy/load) by per-chunk
// asm-memory fences around the LDS bounce; fill kernel proves 6.6 TB/s is
// available. launch_bounds 2nd arg = blocks/CU on this hipcc.
__global__ __launch_bounds__(512, 2) void attn_pv(
    const _Float16* __restrict__ Qh, const _Float16* __restrict__ Kh,
    const _Float16* __restrict__ Vt, float* __restrict__ X, float* __restrict__ Lsum) {
  const int tid = threadIdx.x;
  const int w = tid >> 6;
  const int l = tid & 63;
  const int l15 = l & 15;
  const int lq = l >> 4;
  const int r4 = lq * 4;
  const int bx = blockIdx.x;
  const int b = bx >> 8;
  const int m0 = (bx & 255) * 16;

  const _Float16* qb = Qh + ((size_t)b * S + m0) * D;
  const _Float16* kb = Kh + ((size_t)b * S) * D;
  const _Float16* vtb = Vt + ((size_t)b * D) * S;

  __shared__ float lred[8][16];
  __shared__ __align__(16) float xred[8][16][66];

  // Q as B-frag (col=query=l15, k=8lq+j): same addresses as A-frag form
  half8 qf0 = *(const half8*)(qb + (size_t)l15 * D + lq * 8);
  half8 qf1 = *(const half8*)(qb + (size_t)l15 * D + 32 + lq * 8);

  const int nbase = w * 512;
  const int srcA = (lq & 1) * 32 + l15;   // shfl source lanes for A-frag build
  const int srcB = srcA + 16;
  const bool hi = (lq & 2) != 0;          // frag-half select

  float vsum = 0.f;
  f32x4 xacc[4];
#pragma unroll
  for (int fd = 0; fd < 4; ++fd) xacc[fd] = (f32x4){0.f, 0.f, 0.f, 0.f};

#pragma unroll
  for (int c = 0; c < 8; ++c) {
    int dw[4][2];
    // QK^T swapped: A=K (row=key=l15 within tile), B=Q (col=query=l15)
#pragma unroll
    for (int f = 0; f < 4; ++f) {
      const _Float16* kp = kb + (size_t)(nbase + c * 64 + f * 16 + l15) * D + lq * 8;
      half8 kf0 = *(const half8*)(kp);
      half8 kf1 = *(const half8*)(kp + 32);
      f32x4 a = (f32x4){0.f, 0.f, 0.f, 0.f};
      a = __builtin_amdgcn_mfma_f32_16x16x32_f16(kf0, qf0, a, 0, 0, 0);
      a = __builtin_amdgcn_mfma_f32_16x16x32_f16(kf1, qf1, a, 0, 0, 0);
      // lane holds P[q=l15][key = c*64 + f*16 + 4lq + j]; exp unnormalized
      float p0 = __expf(a[0]), p1 = __expf(a[1]);
      float p2 = __expf(a[2]), p3 = __expf(a[3]);
      vsum += (p0 + p1) + (p2 + p3);
      half2v h01 = {(_Float16)p0, (_Float16)p1};
      half2v h23 = {(_Float16)p2, (_Float16)p3};
      dw[f][0] = __builtin_bit_cast(int, h01);
      dw[f][1] = __builtin_bit_cast(int, h23);
    }
    // PV over two 32-key windows; A-frag = in-register transpose via shfl
#pragma unroll
    for (int w2 = 0; w2 < 2; ++w2) {
      const int f0 = 2 * w2, f1 = 2 * w2 + 1;
      int yA0 = __shfl(dw[f0][0], srcA, 64), yA1 = __shfl(dw[f0][1], srcA, 64);
      int yB0 = __shfl(dw[f0][0], srcB, 64), yB1 = __shfl(dw[f0][1], srcB, 64);
      int xA0 = __shfl(dw[f1][0], srcA, 64), xA1 = __shfl(dw[f1][1], srcA, 64);
      int xB0 = __shfl(dw[f1][0], srcB, 64), xB1 = __shfl(dw[f1][1], srcB, 64);
      int4v ai = {hi ? xA0 : yA0, hi ? xA1 : yA1, hi ? xB0 : yB0, hi ? xB1 : yB1};
      half8 af = __builtin_bit_cast(half8, ai);  // P[q=l15][k=8lq+0..7]
#pragma unroll
      for (int fd = 0; fd < 4; ++fd) {
        half8 bf = *(const half8*)(vtb + (size_t)(fd * 16 + l15) * S +
                                   nbase + c * 64 + w2 * 32 + lq * 8);
        xacc[fd] = __builtin_amdgcn_mfma_f32_16x16x32_f16(af, bf, xacc[fd], 0, 0, 0);
      }
    }
  }

  // row sums: reduce across the 4 lq-lanes sharing query l15
  vsum += __shfl_xor(vsum, 16, 64);
  vsum += __shfl_xor(vsum, 32, 64);
  if (l < 16) lred[w][l] = vsum;
  __syncthreads();

  if (tid < 16) {
    float s = 0.f;
#pragma unroll
    for (int ww = 0; ww < 8; ++ww) s += lred[ww][tid];
    Lsum[(size_t)b * S + m0 + tid] = __logf(s);
  }

  float rinvX[4];
#pragma unroll
  for (int j = 0; j < 4; ++j) {
    float s = 0.f;
#pragma unroll
    for (int ww = 0; ww < 8; ++ww) s += lred[ww][r4 + j];
    rinvX[j] = 1.0f / s;
  }

  // cross-wave reduce of X (xacc layout: X[q=r4+j][d=fd*16+l15])
#pragma unroll
  for (int fd = 0; fd < 4; ++fd)
#pragma unroll
    for (int j = 0; j < 4; ++j)
      xred[w][r4 + j][fd * 16 + l15] = xacc[fd][j] * rinvX[j];
  __syncthreads();
  float* xrow = X + ((size_t)b * S + m0) * D;
#pragma unroll
  for (int o = tid; o < 16 * 64; o += 512) {
    int r = o >> 6, d = o & 63;
    float s = 0.f;
#pragma unroll
    for (int ww = 0; ww < 8; ++ww) s += xred[ww][r][d];
    xrow[(size_t)r * D + d] = s;
  }
}

// ---- Pass 2: A store, zero LDS, zero fences. Swapped QK^T: lane's f32x4 =
// exp(score[key r4..r4+3][query l15] - lsum) -> one contiguous 16B store.
// Pure load->mfma->exp->store dataflow, ~30 regs, (512,4) -> 32 waves/CU. ----
__global__ __launch_bounds__(512, 4) void attn_store(
    const _Float16* __restrict__ Qh, const _Float16* __restrict__ Kh,
    const float* __restrict__ Lsum, float* __restrict__ Aout) {
  const int tid = threadIdx.x;
  const int w = tid >> 6;
  const int l = tid & 63;
  const int l15 = l & 15;
  const int lq = l >> 4;
  const int r4 = lq * 4;
  const int bx = blockIdx.x;
  const int b = bx >> 8;
  const int m0 = (bx & 255) * 16;

  const _Float16* qb = Qh + ((size_t)b * S + m0) * D;
  const _Float16* kb = Kh + ((size_t)b * S) * D;

  half8 qf0 = *(const half8*)(qb + (size_t)l15 * D + lq * 8);
  half8 qf1 = *(const half8*)(qb + (size_t)l15 * D + 32 + lq * 8);

  const float ls = Lsum[(size_t)b * S + m0 + l15];   // this lane's query row
  const int nbase = w * 512;
  float* arow = Aout + ((size_t)(b * S + m0 + l15)) * S + nbase + r4;

#pragma unroll
  for (int c = 0; c < 8; ++c) {
#pragma unroll
    for (int f = 0; f < 4; ++f) {
      const _Float16* kp = kb + (size_t)(nbase + c * 64 + f * 16 + l15) * D + lq * 8;
      half8 kf0 = *(const half8*)(kp);
      half8 kf1 = *(const half8*)(kp + 32);
      f32x4 a = (f32x4){0.f, 0.f, 0.f, 0.f};
      a = __builtin_amdgcn_mfma_f32_16x16x32_f16(kf0, qf0, a, 0, 0, 0);
      a = __builtin_amdgcn_mfma_f32_16x16x32_f16(kf1, qf1, a, 0, 0, 0);
      f32x4 o;
#pragma unroll
      for (int j = 0; j < 4; ++j) o[j] = __expf(a[j] - ls);  // normalized
      *(f32x4*)(arow + c * 64 + f * 16) = o;
    }
  }
}

extern "C" void kernel_launch(void* const* d_in, const int* in_sizes, int n_in,
                              void* d_out, int out_size, void* d_ws, size_t ws_size,
                              hipStream_t stream) {
  const float* Q = (const float*)d_in[0];
  const float* K = (const float*)d_in[1];
  const float* V = (const float*)d_in[2];
  float* X = (float*)d_out;                       // [16,4096,64]
  float* A = X + (size_t)NB * S * D;              // [16,4096,4096]
  _Float16* Qh = (_Float16*)d_ws;
  _Float16* Kh = Qh + (size_t)NB * S * D;
  _Float16* Vt = Kh + (size_t)NB * S * D;
  float* Lsum = (float*)(Vt + (size_t)NB * S * D);  // [16,4096] f32
  int n = NB * S * D;
  cvt_qk<<<2048, 256, 0, stream>>>(Q, K, Qh, Kh, n);
  cvt_vt<<<NB * 64, 256, 0, stream>>>(V, Vt);
  attn_pv<<<NB * 256, 512, 0, stream>>>(Qh, Kh, Vt, X, Lsum);
  attn_store<<<NB * 256, 512, 0, stream>>>(Qh, Kh, Lsum, A);
}